// Round 10
// baseline (126.873 us; speedup 1.0000x reference)
//
#include <hip/hip_runtime.h>
#include <hip/hip_cooperative_groups.h>

namespace cg = cooperative_groups;

// CNF vector field + exact divergence via bilinear-form trick, MFMA edition.
//   dx  = tanh(tanh([x,t]W1+b1)W2+b2)W3+b3, /2
//   div = 0.5 * d1^T (W2 ∘ (W1[:64]^T W3^T)) d2
// R10: single COOPERATIVE kernel (256 blocks x 512 thr, 1 block/CU).
//   Pre-sync: waves 0-3 pack this block's 4 [W2|G] bf16 fragment tiles
//   (content identical to verified R5-R9 pack) WHILE waves 4-7 run layer 1;
//   grid.sync(); then R9's phase-2 MFMA / epilogue / layer-3 body unchanged.
//   Eliminates the pack dispatch + stream drain (launch overhead ~10us/dispatch
//   was the last unexplained slice; phases 2-redesigns were 3x neutral).
// Invariants: 512-thr blocks (1024 => 64-VGPR cap + spills); residue ~63us is
//   harness fill/restore, untouchable; bf16 numerics verified (absmax 3.9e-3).

constexpr int HD = 512;
constexpr int DD = 64;
constexpr int SB = 8;
constexpr int NB = 2048 / SB;   // 256 blocks

typedef __attribute__((ext_vector_type(8))) short bf16x8;
typedef __attribute__((ext_vector_type(4))) float f32x4;

__device__ inline unsigned short f2bf(float f) {
    union { float f; unsigned u; } v; v.f = f;
    return (unsigned short)((v.u + 0x7fffu + ((v.u >> 16) & 1u)) >> 16);
}
__device__ inline float fast_tanh(float xx) {
    float e = __expf(2.f * xx);
    return 1.f - 2.f / (e + 1.f);
}

union SmemBig {
    struct {
        float w1s[64 * 132];   // [i][kl], block's 128 k-cols, pad->132
        float w3s[16 * 65];    // [nn][i], block's 16 n-rows, pad->65
    } pk;                      // 38.0 KB, dead after pack-compute
    float4 h2v[HD * 2];        // 16 KB, live after phase 2
};

__global__ __launch_bounds__(512, 2) void cnf_mega_kernel(
    const float* __restrict__ tptr, const float* __restrict__ x,
    const float* __restrict__ W1, const float* __restrict__ b1,
    const float* __restrict__ W2, const float* __restrict__ b2v,
    const float* __restrict__ W3, const float* __restrict__ b3,
    unsigned short* __restrict__ Bpack, float* __restrict__ out)
{
    __shared__ SmemBig sm;
    __shared__ float4 xsv[65 * 2];             // [i][s0-3],[i][s4-7]
    __shared__ unsigned short A_lds[16][520];  // bf16 A rows; reused as opart
    __shared__ float sm_b2[HD];
    __shared__ float4 divred[8][2];

    const int tid  = threadIdx.x;
    const int blk  = blockIdx.x;
    const int s0   = blk * SB;
    const int wave = tid >> 6, lane = tid & 63;

    // pack-tile coords owned by this block: 256 blocks x 4 kk-tiles = 1024 tiles
    const int mat = blk & 1, t = (blk >> 1) & 31, kkg = blk >> 6;

    // ---- stage: xsv + b2 (all); w1s/w3s (mat==1 blocks) ----
    {
        const float tval = tptr[0];
        for (int e = tid; e < SB * 65; e += 512) {
            int s = e / 65, i = e % 65;
            reinterpret_cast<float*>(xsv)[i * SB + s] =
                (i == DD) ? tval : x[(s0 + s) * 65 + i];
        }
        sm_b2[tid] = b2v[tid];
        if (mat) {
            for (int e = tid; e < 64 * 128; e += 512) {
                int i = e >> 7, kl = e & 127;
                sm.pk.w1s[i * 132 + kl] = W1[i * HD + kkg * 128 + kl];
            }
            for (int e = tid; e < 16 * 64; e += 512) {
                int nn = e >> 6, i = e & 63;
                sm.pk.w3s[nn * 65 + i] = W3[(t * 16 + nn) * DD + i];
            }
        }
    }
    __syncthreads();

    // ---- parallel section: waves 0-3 pack; waves 4-7 layer 1 ----
    if (wave < 4) {
        // pack tile (mat, t, kk): fragment content identical to R5-R9 (verified)
        const int kk = kkg * 4 + wave;
        const int q = lane >> 4, nl = lane & 15;
        const int n = t * 16 + nl;
        unsigned short o[8];
        if (mat == 0) {
#pragma unroll
            for (int j = 0; j < 8; ++j)
                o[j] = f2bf(W2[(kk * 32 + q * 8 + j) * HD + n]);
        } else {
            float s[8];
#pragma unroll
            for (int j = 0; j < 8; ++j) s[j] = 0.f;
            const int kl0 = wave * 32 + q * 8;
#pragma unroll 4
            for (int i = 0; i < 64; ++i) {
                const float w3v = sm.pk.w3s[nl * 65 + i];
#pragma unroll
                for (int j = 0; j < 8; ++j)
                    s[j] += sm.pk.w1s[i * 132 + kl0 + j] * w3v;
            }
#pragma unroll
            for (int j = 0; j < 8; ++j)
                o[j] = f2bf(W2[(kk * 32 + q * 8 + j) * HD + n] * s[j]);
        }
        uint4 pk4;
        pk4.x = (unsigned)o[0] | ((unsigned)o[1] << 16);
        pk4.y = (unsigned)o[2] | ((unsigned)o[3] << 16);
        pk4.z = (unsigned)o[4] | ((unsigned)o[5] << 16);
        pk4.w = (unsigned)o[6] | ((unsigned)o[7] << 16);
        const int w = t >> 2, t8 = mat * 4 + (t & 3);
        reinterpret_cast<uint4*>(Bpack)[((w * 16 + kk) * 8 + t8) * 64 + lane] = pk4;
    } else {
        // layer 1 fp32: 256 threads, 2 units each (u0 and u0+256), 8 samples
        const int u0 = tid - 256;
#pragma unroll
        for (int hu = 0; hu < 2; ++hu) {
            const int u = u0 + hu * 256;
            const float bb = b1[u];
            float2 a0 = {bb, bb}, a1 = {bb, bb}, a2 = {bb, bb}, a3 = {bb, bb};
            for (int ib = 0; ib < 64; ib += 8) {
                float w[8];
#pragma unroll
                for (int qq = 0; qq < 8; ++qq) w[qq] = W1[(ib + qq) * HD + u];
#pragma unroll
                for (int qq = 0; qq < 8; ++qq) {
                    float4 p = xsv[2 * (ib + qq)], r = xsv[2 * (ib + qq) + 1];
                    a0.x += p.x * w[qq]; a0.y += p.y * w[qq];
                    a1.x += p.z * w[qq]; a1.y += p.w * w[qq];
                    a2.x += r.x * w[qq]; a2.y += r.y * w[qq];
                    a3.x += r.z * w[qq]; a3.y += r.w * w[qq];
                }
            }
            {
                float w = W1[64 * HD + u];
                float4 p = xsv[128], r = xsv[129];
                a0.x += p.x * w; a0.y += p.y * w;
                a1.x += p.z * w; a1.y += p.w * w;
                a2.x += r.x * w; a2.y += r.y * w;
                a3.x += r.z * w; a3.y += r.w * w;
            }
            float h[8] = {fast_tanh(a0.x), fast_tanh(a0.y), fast_tanh(a1.x), fast_tanh(a1.y),
                          fast_tanh(a2.x), fast_tanh(a2.y), fast_tanh(a3.x), fast_tanh(a3.y)};
#pragma unroll
            for (int s = 0; s < 8; ++s) {
                A_lds[s][u]     = f2bf(h[s]);
                A_lds[8 + s][u] = f2bf(1.f - h[s] * h[s]);
            }
        }
    }
    __syncthreads();          // A_lds complete block-locally
    cg::this_grid().sync();   // Bpack visible device-wide

    // ---- phase 2: MFMA k-loop, depth-3 rotating pipeline (R9 body) ----
    f32x4 cw[4], cg4[4];
#pragma unroll
    for (int i = 0; i < 4; ++i) { cw[i] = (f32x4){0,0,0,0}; cg4[i] = (f32x4){0,0,0,0}; }
    {
        const bf16x8* bp = reinterpret_cast<const bf16x8*>(Bpack)
                         + (size_t)wave * 8192 + lane;   // frag(kk,j) = bp[kk*512 + j*64]
        const unsigned short* arow = &A_lds[lane & 15][0];
        const int aoff = (lane >> 4) * 8;   // ushorts
        bf16x8 buf[3][8];
#pragma unroll
        for (int j = 0; j < 8; ++j) buf[0][j] = bp[j * 64];
#pragma unroll
        for (int j = 0; j < 8; ++j) buf[1][j] = bp[512 + j * 64];
#pragma unroll
        for (int kk = 0; kk < 16; ++kk) {
            if (kk + 2 < 16) {
#pragma unroll
                for (int j = 0; j < 8; ++j)
                    buf[(kk + 2) % 3][j] = bp[(kk + 2) * 512 + j * 64];
            }
            bf16x8 af = *reinterpret_cast<const bf16x8*>(arow + kk * 32 + aoff);
#pragma unroll
            for (int i = 0; i < 4; ++i)
                cw[i] = __builtin_amdgcn_mfma_f32_16x16x32_bf16(af, buf[kk % 3][i], cw[i], 0, 0, 0);
#pragma unroll
            for (int i = 0; i < 4; ++i)
                cg4[i] = __builtin_amdgcn_mfma_f32_16x16x32_bf16(af, buf[kk % 3][4 + i], cg4[i], 0, 0, 0);
        }
    }

    // ---- epilogue: h2 (lanes 0-31 rows) + div partials (lanes 32-63 rows) ----
    {
        const int qd = lane >> 4;                 // row-quad 0..3
        const int src = (lane >= 32) ? lane - 32 : lane;
        float4 dp = {0.f, 0.f, 0.f, 0.f};
#pragma unroll
        for (int i = 0; i < 4; ++i) {
            const int m = wave * 64 + i * 16 + (lane & 15);
            const float bb = sm_b2[m];
            float4 hv;
            hv.x = fast_tanh(cw[i][0] + bb);
            hv.y = fast_tanh(cw[i][1] + bb);
            hv.z = fast_tanh(cw[i][2] + bb);
            hv.w = fast_tanh(cw[i][3] + bb);
            if (lane < 32) sm.h2v[2 * m + qd] = hv;  // rows 0-7 = h-samples
            float h0 = __shfl(hv.x, src), h1s = __shfl(hv.y, src);
            float h2s = __shfl(hv.z, src), h3s = __shfl(hv.w, src);
            dp.x += cg4[i][0] * (1.f - h0 * h0);
            dp.y += cg4[i][1] * (1.f - h1s * h1s);
            dp.z += cg4[i][2] * (1.f - h2s * h2s);
            dp.w += cg4[i][3] * (1.f - h3s * h3s);
        }
        if (lane >= 32) {
#pragma unroll
            for (int off = 8; off > 0; off >>= 1) {
                dp.x += __shfl_down(dp.x, off, 16);
                dp.y += __shfl_down(dp.y, off, 16);
                dp.z += __shfl_down(dp.z, off, 16);
                dp.w += __shfl_down(dp.w, off, 16);
            }
            if ((lane & 15) == 0) divred[wave][qd - 2] = dp;
        }
    }
    __syncthreads();   // h2v + divred complete; A_lds free

    float* opart = reinterpret_cast<float*>(A_lds);   // 8 x 512 fp32

    // ---- phase 4: layer 3 fp32; part = wave, k = lane; 64 m's per part ----
    {
        const int k = lane, part = wave;
        float o[8];
#pragma unroll
        for (int q = 0; q < 8; ++q) o[q] = 0.f;
        const int mb = part * 64;
        for (int mm = 0; mm < 64; mm += 8) {
            float w[8];
#pragma unroll
            for (int q = 0; q < 8; ++q) w[q] = W3[(mb + mm + q) * DD + k];
#pragma unroll
            for (int q = 0; q < 8; ++q) {
                const int m = mb + mm + q;
                float4 ha = sm.h2v[2 * m], hb = sm.h2v[2 * m + 1];
                o[0] += ha.x * w[q]; o[1] += ha.y * w[q];
                o[2] += ha.z * w[q]; o[3] += ha.w * w[q];
                o[4] += hb.x * w[q]; o[5] += hb.y * w[q];
                o[6] += hb.z * w[q]; o[7] += hb.w * w[q];
            }
        }
#pragma unroll
        for (int q = 0; q < 8; ++q) opart[part * 512 + q * 64 + k] = o[q];
    }
    __syncthreads();

    // ---- outputs ----
    {
        const int s = tid >> 6, k = tid & 63;
        float sum = b3[k];
#pragma unroll
        for (int p = 0; p < 8; ++p) sum += opart[p * 512 + s * 64 + k];
        out[(s0 + s) * 65 + k] = 0.5f * sum;
    }
    if (tid < 8) {
        const int qq = tid >> 2, r = tid & 3;
        float ds = 0.f;
#pragma unroll
        for (int w = 0; w < 8; ++w)
            ds += reinterpret_cast<const float*>(&divred[w][qq])[r];
        out[(s0 + tid) * 65 + DD] = 0.5f * ds;
    }
}

extern "C" void kernel_launch(void* const* d_in, const int* in_sizes, int n_in,
                              void* d_out, int out_size, void* d_ws, size_t ws_size,
                              hipStream_t stream) {
    const float* t  = (const float*)d_in[0];
    const float* x  = (const float*)d_in[1];
    const float* W1 = (const float*)d_in[2];
    const float* b1 = (const float*)d_in[3];
    const float* W2 = (const float*)d_in[4];
    const float* b2 = (const float*)d_in[5];
    const float* W3 = (const float*)d_in[6];
    const float* b3 = (const float*)d_in[7];
    float* out = (float*)d_out;
    unsigned short* Bpack = (unsigned short*)d_ws;   // 2*512*512 bf16 = 1 MB

    void* args[10] = { (void*)&t, (void*)&x, (void*)&W1, (void*)&b1,
                       (void*)&W2, (void*)&b2, (void*)&W3, (void*)&b3,
                       (void*)&Bpack, (void*)&out };
    hipLaunchCooperativeKernel((const void*)cnf_mega_kernel,
                               dim3(NB), dim3(512), args, 0, stream);
}

// Round 11
// 107.652 us; speedup vs baseline: 1.1785x; 1.1785x over previous
//
#include <hip/hip_runtime.h>

// CNF vector field + exact divergence via bilinear-form trick, MFMA edition.
//   dx  = tanh(tanh([x,t]W1+b1)W2+b2)W3+b3, /2
//   div = 0.5 * d1^T (W2 ∘ (W1[:64]^T W3^T)) d2
// R11 = R7 (best, 97.8us) + nontemporal loads on all single-use global streams
//   (B frags, W1, W3). Theory: zero intra-block reuse -> L1 line fills are pure
//   overhead; if TCP line-fill limits streaming rate, nt loads lift it.
// Law learned R7-R10: fused time ~= per-CU bytes / stream-rate; restructures
//   that don't cut per-CU bytes (TLP, prefetch depth, contiguity, coop fusion)
//   are neutral. 512-thr blocks only (1024 => 64-VGPR cap + spills).

constexpr int HD = 512;
constexpr int DD = 64;
constexpr int SB = 8;
constexpr int NB = 2048 / SB;   // 256 blocks

typedef __attribute__((ext_vector_type(8))) short bf16x8;
typedef __attribute__((ext_vector_type(4))) float f32x4;

__device__ inline unsigned short f2bf(float f) {
    union { float f; unsigned u; } v; v.f = f;
    return (unsigned short)((v.u + 0x7fffu + ((v.u >> 16) & 1u)) >> 16);
}
__device__ inline float fast_tanh(float xx) {
    float e = __expf(2.f * xx);
    return 1.f - 2.f / (e + 1.f);
}

// ---------------- pack kernel: Bpack = bf16 fragment-ordered [W2 | G] --------
// chunk c = (mat*32 + t)*16 + kk; lane l: 8 bf16 = B[kk*32+(l>>4)*8+j][t*16+(l&15)]
// (layout verified R5-R7). mat 1 computes G inline.
__global__ __launch_bounds__(64) void cnf_pack_kernel(
    const float* __restrict__ W1, const float* __restrict__ W2,
    const float* __restrict__ W3, unsigned short* __restrict__ Bpack)
{
    __shared__ float w1s[64][33];
    __shared__ float w3s[16][65];
    const int b = blockIdx.x;                 // 0..1023
    const int mat = b >> 9, t = (b >> 4) & 31, kk = b & 15;
    const int l = threadIdx.x;
    const int q = l >> 4, nl = l & 15;
    const int n = t * 16 + nl;
    unsigned short o[8];
    if (mat == 0) {
#pragma unroll
        for (int j = 0; j < 8; ++j) {
            int k = kk * 32 + q * 8 + j;
            o[j] = f2bf(W2[k * HD + n]);
        }
    } else {
        for (int e = l; e < 64 * 32; e += 64) {
            int i = e >> 5, kl = e & 31;
            w1s[i][kl] = W1[i * HD + kk * 32 + kl];
        }
        for (int e = l; e < 16 * 64; e += 64) {
            int nn = e >> 6, i = e & 63;
            w3s[nn][i] = W3[(t * 16 + nn) * DD + i];
        }
        __syncthreads();
#pragma unroll
        for (int j = 0; j < 8; ++j) {
            int kl = q * 8 + j;
            float m = 0.f;
#pragma unroll 8
            for (int i = 0; i < 64; ++i) m += w1s[i][kl] * w3s[nl][i];
            o[j] = f2bf(W2[(kk * 32 + kl) * HD + n] * m);
        }
    }
    uint4 pk;
    pk.x = (unsigned)o[0] | ((unsigned)o[1] << 16);
    pk.y = (unsigned)o[2] | ((unsigned)o[3] << 16);
    pk.z = (unsigned)o[4] | ((unsigned)o[5] << 16);
    pk.w = (unsigned)o[6] | ((unsigned)o[7] << 16);
    reinterpret_cast<uint4*>(Bpack)[b * 64 + l] = pk;
}

// ---------------- fused MLP + divergence, 512 threads ----------------
__global__ __launch_bounds__(512, 2) void cnf_fused_kernel(
    const float* __restrict__ tptr, const float* __restrict__ x,
    const float* __restrict__ W1, const float* __restrict__ b1,
    const float* __restrict__ b2v, const float* __restrict__ W3,
    const float* __restrict__ b3, const unsigned short* __restrict__ Bpack,
    float* __restrict__ out)
{
    __shared__ float4 xsv[65 * 2];             // [i][s0-3],[i][s4-7]
    __shared__ unsigned short A_lds[16][520];  // bf16 A; stride 1040B (16B-aligned)
    __shared__ float4 h2v[HD * 2];             // [m][q]
    __shared__ float4 divred[8][2];
    __shared__ float sm_b2[HD];

    const int tid  = threadIdx.x;
    const int s0   = blockIdx.x * SB;
    const int wave = tid >> 6, lane = tid & 63;

    // ---- phase 0: stage x rows (drop col 64, append t) + b2 ----
    {
        const float tval = tptr[0];
        for (int e = tid; e < SB * 65; e += 512) {
            int s = e / 65, i = e % 65;
            reinterpret_cast<float*>(xsv)[i * SB + s] =
                (i == DD) ? tval : x[(s0 + s) * 65 + i];
        }
        sm_b2[tid] = b2v[tid];
    }
    __syncthreads();

    // ---- phase 1: layer 1 fp32; thread = unit u, all 8 samples ----
    {
        const int u = tid;
        const float bb = b1[u];
        float2 a0 = {bb, bb}, a1 = {bb, bb}, a2 = {bb, bb}, a3 = {bb, bb};
        for (int ib = 0; ib < 64; ib += 8) {
            float w[8];
#pragma unroll
            for (int qq = 0; qq < 8; ++qq)
                w[qq] = __builtin_nontemporal_load(&W1[(ib + qq) * HD + u]);
#pragma unroll
            for (int qq = 0; qq < 8; ++qq) {
                float4 p = xsv[2 * (ib + qq)], r = xsv[2 * (ib + qq) + 1];
                a0.x += p.x * w[qq]; a0.y += p.y * w[qq];
                a1.x += p.z * w[qq]; a1.y += p.w * w[qq];
                a2.x += r.x * w[qq]; a2.y += r.y * w[qq];
                a3.x += r.z * w[qq]; a3.y += r.w * w[qq];
            }
        }
        {
            float w = __builtin_nontemporal_load(&W1[64 * HD + u]);
            float4 p = xsv[128], r = xsv[129];
            a0.x += p.x * w; a0.y += p.y * w;
            a1.x += p.z * w; a1.y += p.w * w;
            a2.x += r.x * w; a2.y += r.y * w;
            a3.x += r.z * w; a3.y += r.w * w;
        }
        float h[8] = {fast_tanh(a0.x), fast_tanh(a0.y), fast_tanh(a1.x), fast_tanh(a1.y),
                      fast_tanh(a2.x), fast_tanh(a2.y), fast_tanh(a3.x), fast_tanh(a3.y)};
#pragma unroll
        for (int s = 0; s < 8; ++s) {
            A_lds[s][u]     = f2bf(h[s]);
            A_lds[8 + s][u] = f2bf(1.f - h[s] * h[s]);
        }
    }
    __syncthreads();

    // ---- phase 2: MFMA. wave w: cols [w*64, w*64+64) of BOTH W2 and G ----
    f32x4 cw[4], cg[4];
#pragma unroll
    for (int i = 0; i < 4; ++i) { cw[i] = (f32x4){0,0,0,0}; cg[i] = (f32x4){0,0,0,0}; }
    {
        const unsigned short* arow = &A_lds[lane & 15][0];
        const int aoff = (lane >> 4) * 8;   // ushorts
        const bf16x8* bw = reinterpret_cast<const bf16x8*>(Bpack)
                         + (size_t)(wave * 64) * 64 + lane;
        const bf16x8* bg = bw + 32768;      // + 32 tiles * 1024 frags

        bf16x8 pA[16], pB[16];              // ping-pong super-batches (2 kk each)
        auto loadSB = [&](bf16x8* d, int kk) {
#pragma unroll
            for (int i = 0; i < 4; ++i) {
                d[i]      = __builtin_nontemporal_load(&bw[kk * 64 + i * 1024]);
                d[4 + i]  = __builtin_nontemporal_load(&bg[kk * 64 + i * 1024]);
                d[8 + i]  = __builtin_nontemporal_load(&bw[(kk + 1) * 64 + i * 1024]);
                d[12 + i] = __builtin_nontemporal_load(&bg[(kk + 1) * 64 + i * 1024]);
            }
        };
        auto mfmaSB = [&](const bf16x8* d, int kk) {
            bf16x8 af0 = *reinterpret_cast<const bf16x8*>(arow + kk * 32 + aoff);
#pragma unroll
            for (int i = 0; i < 4; ++i)
                cw[i] = __builtin_amdgcn_mfma_f32_16x16x32_bf16(af0, d[i], cw[i], 0, 0, 0);
#pragma unroll
            for (int i = 0; i < 4; ++i)
                cg[i] = __builtin_amdgcn_mfma_f32_16x16x32_bf16(af0, d[4 + i], cg[i], 0, 0, 0);
            bf16x8 af1 = *reinterpret_cast<const bf16x8*>(arow + (kk + 1) * 32 + aoff);
#pragma unroll
            for (int i = 0; i < 4; ++i)
                cw[i] = __builtin_amdgcn_mfma_f32_16x16x32_bf16(af1, d[8 + i], cw[i], 0, 0, 0);
#pragma unroll
            for (int i = 0; i < 4; ++i)
                cg[i] = __builtin_amdgcn_mfma_f32_16x16x32_bf16(af1, d[12 + i], cg[i], 0, 0, 0);
        };

        loadSB(pA, 0);
#pragma unroll
        for (int kb = 0; kb < 8; ++kb) {
            bf16x8* cur = (kb & 1) ? pB : pA;
            bf16x8* nxt = (kb & 1) ? pA : pB;
            if (kb < 7) loadSB(nxt, (kb + 1) * 2);
            mfmaSB(cur, kb * 2);
        }
    }

    // ---- epilogue: h2 (lanes 0-31 rows) + div partials (lanes 32-63 rows) ----
    {
        const int q = lane >> 4;                  // row-quad 0..3
        const int src = (lane >= 32) ? lane - 32 : lane;
        float4 dp = {0.f, 0.f, 0.f, 0.f};
#pragma unroll
        for (int i = 0; i < 4; ++i) {
            const int m = wave * 64 + i * 16 + (lane & 15);
            const float bb = sm_b2[m];
            float4 hv;
            hv.x = fast_tanh(cw[i][0] + bb);
            hv.y = fast_tanh(cw[i][1] + bb);
            hv.z = fast_tanh(cw[i][2] + bb);
            hv.w = fast_tanh(cw[i][3] + bb);
            if (lane < 32) h2v[2 * m + q] = hv;   // rows 0-7 = h-samples
            float h0 = __shfl(hv.x, src), h1s = __shfl(hv.y, src);
            float h2s = __shfl(hv.z, src), h3s = __shfl(hv.w, src);
            dp.x += cg[i][0] * (1.f - h0 * h0);
            dp.y += cg[i][1] * (1.f - h1s * h1s);
            dp.z += cg[i][2] * (1.f - h2s * h2s);
            dp.w += cg[i][3] * (1.f - h3s * h3s);
        }
        if (lane >= 32) {
#pragma unroll
            for (int off = 8; off > 0; off >>= 1) {
                dp.x += __shfl_down(dp.x, off, 16);
                dp.y += __shfl_down(dp.y, off, 16);
                dp.z += __shfl_down(dp.z, off, 16);
                dp.w += __shfl_down(dp.w, off, 16);
            }
            if ((lane & 15) == 0) divred[wave][q - 2] = dp;
        }
    }
    __syncthreads();   // h2v + divred complete; A_lds free

    float* opart = reinterpret_cast<float*>(A_lds);   // 8 x 512 fp32

    // ---- phase 4: layer 3 fp32; part = wave, k = lane; 64 m's per part ----
    {
        const int k = lane, part = wave;
        float o[8];
#pragma unroll
        for (int q = 0; q < 8; ++q) o[q] = 0.f;
        const int mb = part * 64;
        for (int mm = 0; mm < 64; mm += 4) {
            float w[4];
#pragma unroll
            for (int q = 0; q < 4; ++q)
                w[q] = __builtin_nontemporal_load(&W3[(mb + mm + q) * DD + k]);
#pragma unroll
            for (int q = 0; q < 4; ++q) {
                const int m = mb + mm + q;
                float4 ha = h2v[2 * m], hb = h2v[2 * m + 1];
                o[0] += ha.x * w[q]; o[1] += ha.y * w[q];
                o[2] += ha.z * w[q]; o[3] += ha.w * w[q];
                o[4] += hb.x * w[q]; o[5] += hb.y * w[q];
                o[6] += hb.z * w[q]; o[7] += hb.w * w[q];
            }
        }
#pragma unroll
        for (int q = 0; q < 8; ++q) opart[part * 512 + q * 64 + k] = o[q];
    }
    __syncthreads();

    // ---- outputs ----
    {
        const int s = tid >> 6, k = tid & 63;
        float sum = b3[k];
#pragma unroll
        for (int p = 0; p < 8; ++p) sum += opart[p * 512 + s * 64 + k];
        out[(s0 + s) * 65 + k] = 0.5f * sum;
    }
    if (tid < 8) {
        const int qq = tid >> 2, r = tid & 3;
        float ds = 0.f;
#pragma unroll
        for (int w = 0; w < 8; ++w)
            ds += reinterpret_cast<const float*>(&divred[w][qq])[r];
        out[(s0 + tid) * 65 + DD] = 0.5f * ds;
    }
}

extern "C" void kernel_launch(void* const* d_in, const int* in_sizes, int n_in,
                              void* d_out, int out_size, void* d_ws, size_t ws_size,
                              hipStream_t stream) {
    const float* t  = (const float*)d_in[0];
    const float* x  = (const float*)d_in[1];
    const float* W1 = (const float*)d_in[2];
    const float* b1 = (const float*)d_in[3];
    const float* W2 = (const float*)d_in[4];
    const float* b2 = (const float*)d_in[5];
    const float* W3 = (const float*)d_in[6];
    const float* b3 = (const float*)d_in[7];
    float* out = (float*)d_out;
    unsigned short* Bpack = (unsigned short*)d_ws;   // 2*512*512 bf16 = 1 MB

    cnf_pack_kernel<<<1024, 64, 0, stream>>>(W1, W2, W3, Bpack);
    cnf_fused_kernel<<<NB, 512, 0, stream>>>(t, x, W1, b1, b2, W3, b3, Bpack, out);
}

// Round 12
// 97.965 us; speedup vs baseline: 1.2951x; 1.0989x over previous
//
#include <hip/hip_runtime.h>

// CNF vector field + exact divergence via bilinear-form trick, MFMA edition.
//   dx  = tanh(tanh([x,t]W1+b1)W2+b2)W3+b3, /2
//   div = 0.5 * d1^T (W2 ∘ (W1[:64]^T W3^T)) d2
// R12 = exact revert to R7 (best: 97.8us). R11's nontemporal loads regressed
//   +10us (nt harms L2-resident streams on gfx950). Session ledger:
//   R7 prefetch +4.5us WIN; R8 TLP-split neutral; R9 stream-layout neutral;
//   R10 coop-fusion -29us FAIL; R11 nt -10us FAIL. Plateau is structural:
//   ~63us harness residue (d_ws 0xAA fill ~40us at 83% HBM peak + restores)
//   + ~35us kernels pinned at the per-CU L2 stream-byte floor.
// Invariants: 512-thr blocks only (1024 => 64-VGPR cap + spills); bf16 pack
//   fragment layout verified (absmax 3.9e-3 vs 21.25e-3 threshold).

constexpr int HD = 512;
constexpr int DD = 64;
constexpr int SB = 8;
constexpr int NB = 2048 / SB;   // 256 blocks

typedef __attribute__((ext_vector_type(8))) short bf16x8;
typedef __attribute__((ext_vector_type(4))) float f32x4;

__device__ inline unsigned short f2bf(float f) {
    union { float f; unsigned u; } v; v.f = f;
    return (unsigned short)((v.u + 0x7fffu + ((v.u >> 16) & 1u)) >> 16);
}
__device__ inline float fast_tanh(float xx) {
    float e = __expf(2.f * xx);
    return 1.f - 2.f / (e + 1.f);
}

// ---------------- pack kernel: Bpack = bf16 fragment-ordered [W2 | G] --------
// chunk c = (mat*32 + t)*16 + kk; lane l: 8 bf16 = B[kk*32+(l>>4)*8+j][t*16+(l&15)]
// (layout verified R5-R7). mat 1 computes G inline.
__global__ __launch_bounds__(64) void cnf_pack_kernel(
    const float* __restrict__ W1, const float* __restrict__ W2,
    const float* __restrict__ W3, unsigned short* __restrict__ Bpack)
{
    __shared__ float w1s[64][33];
    __shared__ float w3s[16][65];
    const int b = blockIdx.x;                 // 0..1023
    const int mat = b >> 9, t = (b >> 4) & 31, kk = b & 15;
    const int l = threadIdx.x;
    const int q = l >> 4, nl = l & 15;
    const int n = t * 16 + nl;
    unsigned short o[8];
    if (mat == 0) {
#pragma unroll
        for (int j = 0; j < 8; ++j) {
            int k = kk * 32 + q * 8 + j;
            o[j] = f2bf(W2[k * HD + n]);
        }
    } else {
        for (int e = l; e < 64 * 32; e += 64) {
            int i = e >> 5, kl = e & 31;
            w1s[i][kl] = W1[i * HD + kk * 32 + kl];
        }
        for (int e = l; e < 16 * 64; e += 64) {
            int nn = e >> 6, i = e & 63;
            w3s[nn][i] = W3[(t * 16 + nn) * DD + i];
        }
        __syncthreads();
#pragma unroll
        for (int j = 0; j < 8; ++j) {
            int kl = q * 8 + j;
            float m = 0.f;
#pragma unroll 8
            for (int i = 0; i < 64; ++i) m += w1s[i][kl] * w3s[nl][i];
            o[j] = f2bf(W2[(kk * 32 + kl) * HD + n] * m);
        }
    }
    uint4 pk;
    pk.x = (unsigned)o[0] | ((unsigned)o[1] << 16);
    pk.y = (unsigned)o[2] | ((unsigned)o[3] << 16);
    pk.z = (unsigned)o[4] | ((unsigned)o[5] << 16);
    pk.w = (unsigned)o[6] | ((unsigned)o[7] << 16);
    reinterpret_cast<uint4*>(Bpack)[b * 64 + l] = pk;
}

// ---------------- fused MLP + divergence, 512 threads ----------------
__global__ __launch_bounds__(512, 2) void cnf_fused_kernel(
    const float* __restrict__ tptr, const float* __restrict__ x,
    const float* __restrict__ W1, const float* __restrict__ b1,
    const float* __restrict__ b2v, const float* __restrict__ W3,
    const float* __restrict__ b3, const unsigned short* __restrict__ Bpack,
    float* __restrict__ out)
{
    __shared__ float4 xsv[65 * 2];             // [i][s0-3],[i][s4-7]
    __shared__ unsigned short A_lds[16][520];  // bf16 A; stride 1040B (16B-aligned)
    __shared__ float4 h2v[HD * 2];             // [m][q]
    __shared__ float4 divred[8][2];
    __shared__ float sm_b2[HD];

    const int tid  = threadIdx.x;
    const int s0   = blockIdx.x * SB;
    const int wave = tid >> 6, lane = tid & 63;

    // ---- phase 0: stage x rows (drop col 64, append t) + b2 ----
    {
        const float tval = tptr[0];
        for (int e = tid; e < SB * 65; e += 512) {
            int s = e / 65, i = e % 65;
            reinterpret_cast<float*>(xsv)[i * SB + s] =
                (i == DD) ? tval : x[(s0 + s) * 65 + i];
        }
        sm_b2[tid] = b2v[tid];
    }
    __syncthreads();

    // ---- phase 1: layer 1 fp32; thread = unit u, all 8 samples ----
    {
        const int u = tid;
        const float bb = b1[u];
        float2 a0 = {bb, bb}, a1 = {bb, bb}, a2 = {bb, bb}, a3 = {bb, bb};
        for (int ib = 0; ib < 64; ib += 8) {
            float w[8];
#pragma unroll
            for (int qq = 0; qq < 8; ++qq) w[qq] = W1[(ib + qq) * HD + u];
#pragma unroll
            for (int qq = 0; qq < 8; ++qq) {
                float4 p = xsv[2 * (ib + qq)], r = xsv[2 * (ib + qq) + 1];
                a0.x += p.x * w[qq]; a0.y += p.y * w[qq];
                a1.x += p.z * w[qq]; a1.y += p.w * w[qq];
                a2.x += r.x * w[qq]; a2.y += r.y * w[qq];
                a3.x += r.z * w[qq]; a3.y += r.w * w[qq];
            }
        }
        {
            float w = W1[64 * HD + u];
            float4 p = xsv[128], r = xsv[129];
            a0.x += p.x * w; a0.y += p.y * w;
            a1.x += p.z * w; a1.y += p.w * w;
            a2.x += r.x * w; a2.y += r.y * w;
            a3.x += r.z * w; a3.y += r.w * w;
        }
        float h[8] = {fast_tanh(a0.x), fast_tanh(a0.y), fast_tanh(a1.x), fast_tanh(a1.y),
                      fast_tanh(a2.x), fast_tanh(a2.y), fast_tanh(a3.x), fast_tanh(a3.y)};
#pragma unroll
        for (int s = 0; s < 8; ++s) {
            A_lds[s][tid]     = f2bf(h[s]);
            A_lds[8 + s][tid] = f2bf(1.f - h[s] * h[s]);
        }
    }
    __syncthreads();

    // ---- phase 2: MFMA. wave w: cols [w*64, w*64+64) of BOTH W2 and G ----
    f32x4 cw[4], cg[4];
#pragma unroll
    for (int i = 0; i < 4; ++i) { cw[i] = (f32x4){0,0,0,0}; cg[i] = (f32x4){0,0,0,0}; }
    {
        const unsigned short* arow = &A_lds[lane & 15][0];
        const int aoff = (lane >> 4) * 8;   // ushorts
        const bf16x8* bw = reinterpret_cast<const bf16x8*>(Bpack)
                         + (size_t)(wave * 64) * 64 + lane;
        const bf16x8* bg = bw + 32768;      // + 32 tiles * 1024 frags

        bf16x8 pA[16], pB[16];              // ping-pong super-batches (2 kk each)
        auto loadSB = [&](bf16x8* d, int kk) {
#pragma unroll
            for (int i = 0; i < 4; ++i) {
                d[i]      = bw[kk * 64 + i * 1024];
                d[4 + i]  = bg[kk * 64 + i * 1024];
                d[8 + i]  = bw[(kk + 1) * 64 + i * 1024];
                d[12 + i] = bg[(kk + 1) * 64 + i * 1024];
            }
        };
        auto mfmaSB = [&](const bf16x8* d, int kk) {
            bf16x8 af0 = *reinterpret_cast<const bf16x8*>(arow + kk * 32 + aoff);
#pragma unroll
            for (int i = 0; i < 4; ++i)
                cw[i] = __builtin_amdgcn_mfma_f32_16x16x32_bf16(af0, d[i], cw[i], 0, 0, 0);
#pragma unroll
            for (int i = 0; i < 4; ++i)
                cg[i] = __builtin_amdgcn_mfma_f32_16x16x32_bf16(af0, d[4 + i], cg[i], 0, 0, 0);
            bf16x8 af1 = *reinterpret_cast<const bf16x8*>(arow + (kk + 1) * 32 + aoff);
#pragma unroll
            for (int i = 0; i < 4; ++i)
                cw[i] = __builtin_amdgcn_mfma_f32_16x16x32_bf16(af1, d[8 + i], cw[i], 0, 0, 0);
#pragma unroll
            for (int i = 0; i < 4; ++i)
                cg[i] = __builtin_amdgcn_mfma_f32_16x16x32_bf16(af1, d[12 + i], cg[i], 0, 0, 0);
        };

        loadSB(pA, 0);
#pragma unroll
        for (int kb = 0; kb < 8; ++kb) {
            bf16x8* cur = (kb & 1) ? pB : pA;
            bf16x8* nxt = (kb & 1) ? pA : pB;
            if (kb < 7) loadSB(nxt, (kb + 1) * 2);
            mfmaSB(cur, kb * 2);
        }
    }

    // ---- epilogue: h2 (lanes 0-31 rows) + div partials (lanes 32-63 rows) ----
    {
        const int q = lane >> 4;                  // row-quad 0..3
        const int src = (lane >= 32) ? lane - 32 : lane;
        float4 dp = {0.f, 0.f, 0.f, 0.f};
#pragma unroll
        for (int i = 0; i < 4; ++i) {
            const int m = wave * 64 + i * 16 + (lane & 15);
            const float bb = sm_b2[m];
            float4 hv;
            hv.x = fast_tanh(cw[i][0] + bb);
            hv.y = fast_tanh(cw[i][1] + bb);
            hv.z = fast_tanh(cw[i][2] + bb);
            hv.w = fast_tanh(cw[i][3] + bb);
            if (lane < 32) h2v[2 * m + q] = hv;   // rows 0-7 = h-samples
            float h0 = __shfl(hv.x, src), h1s = __shfl(hv.y, src);
            float h2s = __shfl(hv.z, src), h3s = __shfl(hv.w, src);
            dp.x += cg[i][0] * (1.f - h0 * h0);
            dp.y += cg[i][1] * (1.f - h1s * h1s);
            dp.z += cg[i][2] * (1.f - h2s * h2s);
            dp.w += cg[i][3] * (1.f - h3s * h3s);
        }
        if (lane >= 32) {
#pragma unroll
            for (int off = 8; off > 0; off >>= 1) {
                dp.x += __shfl_down(dp.x, off, 16);
                dp.y += __shfl_down(dp.y, off, 16);
                dp.z += __shfl_down(dp.z, off, 16);
                dp.w += __shfl_down(dp.w, off, 16);
            }
            if ((lane & 15) == 0) divred[wave][q - 2] = dp;
        }
    }
    __syncthreads();   // h2v + divred complete; A_lds free

    float* opart = reinterpret_cast<float*>(A_lds);   // 8 x 512 fp32

    // ---- phase 4: layer 3 fp32; part = wave, k = lane; 64 m's per part ----
    {
        const int k = lane, part = wave;
        float o[8];
#pragma unroll
        for (int q = 0; q < 8; ++q) o[q] = 0.f;
        const int mb = part * 64;
        for (int mm = 0; mm < 64; mm += 4) {
            float w[4];
#pragma unroll
            for (int q = 0; q < 4; ++q) w[q] = W3[(mb + mm + q) * DD + k];
#pragma unroll
            for (int q = 0; q < 4; ++q) {
                const int m = mb + mm + q;
                float4 ha = h2v[2 * m], hb = h2v[2 * m + 1];
                o[0] += ha.x * w[q]; o[1] += ha.y * w[q];
                o[2] += ha.z * w[q]; o[3] += ha.w * w[q];
                o[4] += hb.x * w[q]; o[5] += hb.y * w[q];
                o[6] += hb.z * w[q]; o[7] += hb.w * w[q];
            }
        }
#pragma unroll
        for (int q = 0; q < 8; ++q) opart[part * 512 + q * 64 + k] = o[q];
    }
    __syncthreads();

    // ---- outputs ----
    {
        const int s = tid >> 6, k = tid & 63;
        float sum = b3[k];
#pragma unroll
        for (int p = 0; p < 8; ++p) sum += opart[p * 512 + s * 64 + k];
        out[(s0 + s) * 65 + k] = 0.5f * sum;
    }
    if (tid < 8) {
        const int qq = tid >> 2, r = tid & 3;
        float ds = 0.f;
#pragma unroll
        for (int w = 0; w < 8; ++w)
            ds += reinterpret_cast<const float*>(&divred[w][qq])[r];
        out[(s0 + tid) * 65 + DD] = 0.5f * ds;
    }
}

extern "C" void kernel_launch(void* const* d_in, const int* in_sizes, int n_in,
                              void* d_out, int out_size, void* d_ws, size_t ws_size,
                              hipStream_t stream) {
    const float* t  = (const float*)d_in[0];
    const float* x  = (const float*)d_in[1];
    const float* W1 = (const float*)d_in[2];
    const float* b1 = (const float*)d_in[3];
    const float* W2 = (const float*)d_in[4];
    const float* b2 = (const float*)d_in[5];
    const float* W3 = (const float*)d_in[6];
    const float* b3 = (const float*)d_in[7];
    float* out = (float*)d_out;
    unsigned short* Bpack = (unsigned short*)d_ws;   // 2*512*512 bf16 = 1 MB

    cnf_pack_kernel<<<1024, 64, 0, stream>>>(W1, W2, W3, Bpack);
    cnf_fused_kernel<<<NB, 512, 0, stream>>>(t, x, W1, b1, b2, W3, b3, Bpack, out);
}